// Round 3
// baseline (1719.424 us; speedup 1.0000x reference)
//
#include <hip/hip_runtime.h>

#define T_STEPS 1000
#define BATCH   256
#define NHID    200
#define ROWF    204      // floats per LDS row: 200 weights + W2[i] + 3 zero pad
#define BETA_C  0.85f
#define THR_C   1.0f

// Row i of WT2 holds, at float offset l*4+k (l<50,k<4): Wrec[(l+50k)][i],
// and at offset 200: W2[i]. Lane l does ONE ds_read_b128 per firing neuron i.
// Lane 50's float4 starts at offset 200 -> .x = W2[i], so its rec0
// accumulates cur2 for free, in the same sparse order.

__launch_bounds__(64, 1)
__global__ void rsnn_kernel(const float* __restrict__ X,
                            const float* __restrict__ W1,
                            const float* __restrict__ b1,
                            const float* __restrict__ Wrec,
                            const float* __restrict__ brec,
                            const float* __restrict__ W2,
                            const float* __restrict__ b2,
                            float* __restrict__ out_cur2,
                            float* __restrict__ out_spk) {
#pragma clang fp contract(off)
    __shared__ float WT2[40852];   // 163,408 B

    const int l = threadIdx.x;
    const int b = blockIdx.x;

    // ---- stage Wrec (permuted transpose) + W2 into LDS; zero all pads ----
    for (int idx = l; idx < NHID * NHID; idx += 64) {
        int r  = idx / NHID;            // Wrec row  (output neuron)
        int i  = idx - r * NHID;        // Wrec col  (source neuron)
        int lo = r % 50, k = r / 50;
        WT2[i * ROWF + lo * 4 + k] = Wrec[idx];
    }
    for (int i = l; i < NHID; i += 64) {
        WT2[i * ROWF + 200] = W2[i];
        WT2[i * ROWF + 201] = 0.f;
        WT2[i * ROWF + 202] = 0.f;
        WT2[i * ROWF + 203] = 0.f;
    }
    for (int i = 40800 + l; i < 40852; i += 64) WT2[i] = 0.f;
    __syncthreads();

    const int lc = (l < 50) ? l : 49;
    float w1r[4][3], b1r[4], brr[4];
#pragma unroll
    for (int k = 0; k < 4; ++k) {
        int i = lc + 50 * k;
        w1r[k][0] = W1[i * 3 + 0];
        w1r[k][1] = W1[i * 3 + 1];
        w1r[k][2] = W1[i * 3 + 2];
        b1r[k] = b1[i];
        brr[k] = brec[i];
    }
    const float b2v = b2[0];

    float mem0 = 0.f, mem1 = 0.f, mem2 = 0.f, mem3 = 0.f;
    unsigned long long bm0 = 0, bm1 = 0, bm2 = 0, bm3 = 0;

    const float* xp = X + (size_t)b * 3;
    float x0 = xp[0], x1 = xp[1], x2 = xp[2];

    float*       spk_base = out_spk + (size_t)b * NHID + lc;
    const float* ldsrow   = WT2 + (size_t)l * 4;

// One static slot: sentinel bit 50 makes ctz defined when empty; clamp keeps the
// (gated, discarded) load in-bounds; fma with sel in {0,1} is bit-exact.
#define SLOT(P, K, MV, BASE)                                                        \
    unsigned long long mm_##P##K = (MV) | (1ull << 50);                             \
    int   raw_##P##K = __builtin_ctzll(mm_##P##K);                                  \
    int   i_##P##K   = raw_##P##K > 49 ? 49 : raw_##P##K;                           \
    float s_##P##K   = ((MV) != 0ull) ? 1.0f : 0.0f;                                \
    MV &= (MV - 1);                                                                 \
    const float4 v_##P##K = *(const float4*)(ldsrow + (i_##P##K + (BASE)) * ROWF);

#define ISSUE12(P, MV, BASE)                                                        \
    SLOT(P, 0, MV, BASE) SLOT(P, 1, MV, BASE) SLOT(P, 2,  MV, BASE)                 \
    SLOT(P, 3, MV, BASE) SLOT(P, 4, MV, BASE) SLOT(P, 5,  MV, BASE)                 \
    SLOT(P, 6, MV, BASE) SLOT(P, 7, MV, BASE) SLOT(P, 8,  MV, BASE)                 \
    SLOT(P, 9, MV, BASE) SLOT(P,10, MV, BASE) SLOT(P,11,  MV, BASE)

#define ACC1(P, K)                                  \
    rec0 = fmaf(s_##P##K, v_##P##K.x, rec0);        \
    rec1 = fmaf(s_##P##K, v_##P##K.y, rec1);        \
    rec2 = fmaf(s_##P##K, v_##P##K.z, rec2);        \
    rec3 = fmaf(s_##P##K, v_##P##K.w, rec3);

#define ACC12(P)                                    \
    ACC1(P,0) ACC1(P,1) ACC1(P,2)  ACC1(P,3)        \
    ACC1(P,4) ACC1(P,5) ACC1(P,6)  ACC1(P,7)        \
    ACC1(P,8) ACC1(P,9) ACC1(P,10) ACC1(P,11)

#define LWORD(MV, BASE)                                                             \
    while (MV) {                                                                    \
        int i = __builtin_ctzll(MV); MV &= (MV) - 1;                                \
        const float4 v = *(const float4*)(ldsrow + (i + (BASE)) * ROWF);            \
        rec0 += v.x; rec1 += v.y; rec2 += v.z; rec3 += v.w;                         \
    }

    for (int t = 0; t < T_STEPS; ++t) {
        // prefetch next step's input (used one iteration later)
        int   tn  = (t + 1 < T_STEPS) ? t + 1 : t;
        float nx0 = xp[(size_t)tn * BATCH * 3 + 0];
        float nx1 = xp[(size_t)tn * BATCH * 3 + 1];
        float nx2 = xp[(size_t)tn * BATCH * 3 + 2];

        // ---- sparse recurrent gather: issue-all, depth-2 pipelined ----
        unsigned long long m0 = bm0, m1 = bm1, m2 = bm2, m3 = bm3;
        float rec0 = 0.f, rec1 = 0.f, rec2 = 0.f, rec3 = 0.f;

        ISSUE12(A, m0, 0)
        ISSUE12(B, m1, 50)
        ACC12(A)
        ISSUE12(C, m2, 100)
        ACC12(B)
        ISSUE12(D, m3, 150)
        ACC12(C)
        ACC12(D)

        if (m0 | m1 | m2 | m3) {   // rare: >12 firing in a word
            LWORD(m0, 0) LWORD(m1, 50) LWORD(m2, 100) LWORD(m3, 150)
        }

        // lane 50's rec0 = sum of W2 over firing set of step t-1 = cur2_{t-1}
        if (t > 0 && l == 50)
            out_cur2[(size_t)(t - 1) * BATCH + b] = rec0 + b2v;

        // ---- membrane update (numpy op/rounding order preserved) ----
        float c0 = fmaf(x2, w1r[0][2], fmaf(x1, w1r[0][1], x0 * w1r[0][0])) + b1r[0];
        float c1 = fmaf(x2, w1r[1][2], fmaf(x1, w1r[1][1], x0 * w1r[1][0])) + b1r[1];
        float c2 = fmaf(x2, w1r[2][2], fmaf(x1, w1r[2][1], x0 * w1r[2][0])) + b1r[2];
        float c3 = fmaf(x2, w1r[3][2], fmaf(x1, w1r[3][1], x0 * w1r[3][0])) + b1r[3];

        float ba0 = ((BETA_C * mem0 + c0) + rec0) + brr[0];
        float ba1 = ((BETA_C * mem1 + c1) + rec1) + brr[1];
        float ba2 = ((BETA_C * mem2 + c2) + rec2) + brr[2];
        float ba3 = ((BETA_C * mem3 + c3) + rec3) + brr[3];

        float nm0 = (mem0 > THR_C) ? 0.f : ba0;
        float nm1 = (mem1 > THR_C) ? 0.f : ba1;
        float nm2 = (mem2 > THR_C) ? 0.f : ba2;
        float nm3 = (mem3 > THR_C) ? 0.f : ba3;

        float sp0 = (nm0 > THR_C) ? 1.f : 0.f;
        float sp1 = (nm1 > THR_C) ? 1.f : 0.f;
        float sp2 = (nm2 > THR_C) ? 1.f : 0.f;
        float sp3 = (nm3 > THR_C) ? 1.f : 0.f;

        mem0 = nm0; mem1 = nm1; mem2 = nm2; mem3 = nm3;

        // ---- record spikes (fire-and-forget coalesced stores, no barrier) ----
        if (l < 50) {
            float* sb = spk_base + (size_t)t * BATCH * NHID;
            sb[0]   = sp0;
            sb[50]  = sp1;
            sb[100] = sp2;
            sb[150] = sp3;
        }

        // ---- publish wave-uniform spike masks for next step ----
        bm0 = __ballot((l < 50) && (sp0 > 0.5f));
        bm1 = __ballot((l < 50) && (sp1 > 0.5f));
        bm2 = __ballot((l < 50) && (sp2 > 0.5f));
        bm3 = __ballot((l < 50) && (sp3 > 0.5f));

        x0 = nx0; x1 = nx1; x2 = nx2;
    }

    // ---- epilogue: cur2_{T-1} from final spike masks (same ascending order) ----
    {
        float c2f = 0.f;
        unsigned long long ms0 = bm0, ms1 = bm1, ms2 = bm2, ms3 = bm3;
#define C2_WORD(M, BASE)                                             \
        {                                                            \
            unsigned long long m = (M);                              \
            while (m) {                                              \
                int i = __builtin_ctzll(m) + (BASE); m &= m - 1;     \
                c2f += WT2[i * ROWF + 200];                          \
            }                                                        \
        }
        C2_WORD(ms0, 0) C2_WORD(ms1, 50) C2_WORD(ms2, 100) C2_WORD(ms3, 150)
        if (l == 50)
            out_cur2[(size_t)(T_STEPS - 1) * BATCH + b] = c2f + b2v;
#undef C2_WORD
    }
}

extern "C" void kernel_launch(void* const* d_in, const int* in_sizes, int n_in,
                              void* d_out, int out_size, void* d_ws, size_t ws_size,
                              hipStream_t stream) {
    const float* X    = (const float*)d_in[0];
    const float* W1   = (const float*)d_in[1];
    const float* b1   = (const float*)d_in[2];
    const float* Wrec = (const float*)d_in[3];
    const float* brec = (const float*)d_in[4];
    const float* W2   = (const float*)d_in[5];
    const float* b2   = (const float*)d_in[6];

    float* out_cur2 = (float*)d_out;                            // [T,B,1] flat
    float* out_spk  = (float*)d_out + (size_t)T_STEPS * BATCH;  // [T,B,200] flat

    rsnn_kernel<<<BATCH, 64, 0, stream>>>(X, W1, b1, Wrec, brec, W2, b2,
                                          out_cur2, out_spk);
}

// Round 4
// 990.157 us; speedup vs baseline: 1.7365x; 1.7365x over previous
//
#include <hip/hip_runtime.h>

#define T_STEPS 1000
#define BATCH   256
#define NHID    200
#define ROWF    204      // floats per LDS row: 200 weights + W2[i] + 3 zero pad
#define BETA_C  0.85f
#define THR_C   1.0f
#define SENT    (1ull << 50)

// Row i of WT2 holds, at float offset l*4+k (l<50,k<4): Wrec[(l+50k)][i],
// and at offset 200: W2[i]. Lane l does ONE ds_read_b128 per firing neuron i.
// Lane 50's float4 starts at offset 200 -> .x = W2[i], so its rec0
// accumulates cur2 for free, in the same sparse order.

__launch_bounds__(64, 1)
__global__ void rsnn_kernel(const float* __restrict__ X,
                            const float* __restrict__ W1,
                            const float* __restrict__ b1,
                            const float* __restrict__ Wrec,
                            const float* __restrict__ brec,
                            const float* __restrict__ W2,
                            const float* __restrict__ b2,
                            float* __restrict__ out_cur2,
                            float* __restrict__ out_spk) {
#pragma clang fp contract(off)
    __shared__ float WT2[40852];   // 163,408 B

    const int l = threadIdx.x;
    const int b = blockIdx.x;

    // ---- stage Wrec (permuted transpose) + W2 into LDS; zero all pads ----
    for (int idx = l; idx < NHID * NHID; idx += 64) {
        int r  = idx / NHID;            // Wrec row  (output neuron)
        int i  = idx - r * NHID;        // Wrec col  (source neuron)
        int lo = r % 50, k = r / 50;
        WT2[i * ROWF + lo * 4 + k] = Wrec[idx];
    }
    for (int i = l; i < NHID; i += 64) {
        WT2[i * ROWF + 200] = W2[i];
        WT2[i * ROWF + 201] = 0.f;
        WT2[i * ROWF + 202] = 0.f;
        WT2[i * ROWF + 203] = 0.f;
    }
    for (int i = 40800 + l; i < 40852; i += 64) WT2[i] = 0.f;
    __syncthreads();

    const int lc = (l < 50) ? l : 49;
    float w1r[4][3], b1r[4], brr[4];
#pragma unroll
    for (int k = 0; k < 4; ++k) {
        int i = lc + 50 * k;
        w1r[k][0] = W1[i * 3 + 0];
        w1r[k][1] = W1[i * 3 + 1];
        w1r[k][2] = W1[i * 3 + 2];
        b1r[k] = b1[i];
        brr[k] = brec[i];
    }
    const float b2v = b2[0];

    float mem0 = 0.f, mem1 = 0.f, mem2 = 0.f, mem3 = 0.f;
    unsigned long long bm0 = 0, bm1 = 0, bm2 = 0, bm3 = 0;

    const float* xp = X + (size_t)b * 3;
    float x0 = xp[0], x1 = xp[1], x2 = xp[2];

    float*       spk_base = out_spk + (size_t)b * NHID + lc;
    const float* ldsrow   = WT2 + (size_t)l * 4;

// Accumulate the pending (previous) group: fma with sel in {0,1} is bit-exact.
#define ACC_PEND                                                       \
    rec0 = fmaf(pps0, ppv0.x, rec0); rec1 = fmaf(pps0, ppv0.y, rec1);  \
    rec2 = fmaf(pps0, ppv0.z, rec2); rec3 = fmaf(pps0, ppv0.w, rec3);  \
    rec0 = fmaf(pps1, ppv1.x, rec0); rec1 = fmaf(pps1, ppv1.y, rec1);  \
    rec2 = fmaf(pps1, ppv1.z, rec2); rec3 = fmaf(pps1, ppv1.w, rec3);  \
    rec0 = fmaf(pps2, ppv2.x, rec0); rec1 = fmaf(pps2, ppv2.y, rec1);  \
    rec2 = fmaf(pps2, ppv2.z, rec2); rec3 = fmaf(pps2, ppv2.w, rec3);  \
    rec0 = fmaf(pps3, ppv3.x, rec0); rec1 = fmaf(pps3, ppv3.y, rec1);  \
    rec2 = fmaf(pps3, ppv3.z, rec2); rec3 = fmaf(pps3, ppv3.w, rec3);

// Depth-2 pipelined word loop: issue group k, accumulate group k-1.
// Slot 0 always valid (loop guard); slots 1-3 sentinel/clamped and 0/1-gated.
#define PWORD(MASK, BASE)                                                           \
    {                                                                               \
        unsigned long long m = (MASK);                                              \
        while (m) {                                                                 \
            int i0 = __builtin_ctzll(m); m &= m - 1;                                \
            float s1 = (m != 0ull) ? 1.f : 0.f;                                     \
            int r1 = __builtin_ctzll(m | SENT); int i1 = r1 > 49 ? 49 : r1;         \
            m &= m - 1;                                                             \
            float s2 = (m != 0ull) ? 1.f : 0.f;                                     \
            int r2 = __builtin_ctzll(m | SENT); int i2 = r2 > 49 ? 49 : r2;         \
            m &= m - 1;                                                             \
            float s3 = (m != 0ull) ? 1.f : 0.f;                                     \
            int r3 = __builtin_ctzll(m | SENT); int i3 = r3 > 49 ? 49 : r3;         \
            m &= m - 1;                                                             \
            const float4 n0 = *(const float4*)(ldsrow + (i0 + (BASE)) * ROWF);      \
            const float4 n1 = *(const float4*)(ldsrow + (i1 + (BASE)) * ROWF);      \
            const float4 n2 = *(const float4*)(ldsrow + (i2 + (BASE)) * ROWF);      \
            const float4 n3 = *(const float4*)(ldsrow + (i3 + (BASE)) * ROWF);      \
            ACC_PEND                                                                \
            ppv0 = n0; ppv1 = n1; ppv2 = n2; ppv3 = n3;                             \
            pps0 = 1.f; pps1 = s1; pps2 = s2; pps3 = s3;                            \
        }                                                                           \
    }

    for (int t = 0; t < T_STEPS; ++t) {
        // prefetch next step's input (used one iteration later)
        int   tn  = (t + 1 < T_STEPS) ? t + 1 : t;
        float nx0 = xp[(size_t)tn * BATCH * 3 + 0];
        float nx1 = xp[(size_t)tn * BATCH * 3 + 1];
        float nx2 = xp[(size_t)tn * BATCH * 3 + 2];

        // ---- sparse recurrent gather: depth-2 pipelined over groups ----
        float rec0 = 0.f, rec1 = 0.f, rec2 = 0.f, rec3 = 0.f;
        float4 ppv0 = float4{0.f, 0.f, 0.f, 0.f};
        float4 ppv1 = ppv0, ppv2 = ppv0, ppv3 = ppv0;
        float pps0 = 0.f, pps1 = 0.f, pps2 = 0.f, pps3 = 0.f;

        PWORD(bm0, 0)
        PWORD(bm1, 50)
        PWORD(bm2, 100)
        PWORD(bm3, 150)
        ACC_PEND   // drain last pending group

        // lane 50's rec0 = sum of W2 over firing set of step t-1 = cur2_{t-1}
        if (t > 0 && l == 50)
            out_cur2[(size_t)(t - 1) * BATCH + b] = rec0 + b2v;

        // ---- membrane update (numpy op/rounding order preserved) ----
        float c0 = fmaf(x2, w1r[0][2], fmaf(x1, w1r[0][1], x0 * w1r[0][0])) + b1r[0];
        float c1 = fmaf(x2, w1r[1][2], fmaf(x1, w1r[1][1], x0 * w1r[1][0])) + b1r[1];
        float c2 = fmaf(x2, w1r[2][2], fmaf(x1, w1r[2][1], x0 * w1r[2][0])) + b1r[2];
        float c3 = fmaf(x2, w1r[3][2], fmaf(x1, w1r[3][1], x0 * w1r[3][0])) + b1r[3];

        float ba0 = ((BETA_C * mem0 + c0) + rec0) + brr[0];
        float ba1 = ((BETA_C * mem1 + c1) + rec1) + brr[1];
        float ba2 = ((BETA_C * mem2 + c2) + rec2) + brr[2];
        float ba3 = ((BETA_C * mem3 + c3) + rec3) + brr[3];

        float nm0 = (mem0 > THR_C) ? 0.f : ba0;
        float nm1 = (mem1 > THR_C) ? 0.f : ba1;
        float nm2 = (mem2 > THR_C) ? 0.f : ba2;
        float nm3 = (mem3 > THR_C) ? 0.f : ba3;

        float sp0 = (nm0 > THR_C) ? 1.f : 0.f;
        float sp1 = (nm1 > THR_C) ? 1.f : 0.f;
        float sp2 = (nm2 > THR_C) ? 1.f : 0.f;
        float sp3 = (nm3 > THR_C) ? 1.f : 0.f;

        mem0 = nm0; mem1 = nm1; mem2 = nm2; mem3 = nm3;

        // ---- record spikes (fire-and-forget coalesced stores, no barrier) ----
        if (l < 50) {
            float* sb = spk_base + (size_t)t * BATCH * NHID;
            sb[0]   = sp0;
            sb[50]  = sp1;
            sb[100] = sp2;
            sb[150] = sp3;
        }

        // ---- publish wave-uniform spike masks for next step ----
        bm0 = __ballot((l < 50) && (sp0 > 0.5f));
        bm1 = __ballot((l < 50) && (sp1 > 0.5f));
        bm2 = __ballot((l < 50) && (sp2 > 0.5f));
        bm3 = __ballot((l < 50) && (sp3 > 0.5f));

        x0 = nx0; x1 = nx1; x2 = nx2;
    }

    // ---- epilogue: cur2_{T-1} from final spike masks (same ascending order) ----
    {
        float c2f = 0.f;
        unsigned long long ms0 = bm0, ms1 = bm1, ms2 = bm2, ms3 = bm3;
#define C2_WORD(M, BASE)                                             \
        {                                                            \
            unsigned long long m = (M);                              \
            while (m) {                                              \
                int i = __builtin_ctzll(m) + (BASE); m &= m - 1;     \
                c2f += WT2[i * ROWF + 200];                          \
            }                                                        \
        }
        C2_WORD(ms0, 0) C2_WORD(ms1, 50) C2_WORD(ms2, 100) C2_WORD(ms3, 150)
        if (l == 50)
            out_cur2[(size_t)(T_STEPS - 1) * BATCH + b] = c2f + b2v;
#undef C2_WORD
    }
}

extern "C" void kernel_launch(void* const* d_in, const int* in_sizes, int n_in,
                              void* d_out, int out_size, void* d_ws, size_t ws_size,
                              hipStream_t stream) {
    const float* X    = (const float*)d_in[0];
    const float* W1   = (const float*)d_in[1];
    const float* b1   = (const float*)d_in[2];
    const float* Wrec = (const float*)d_in[3];
    const float* brec = (const float*)d_in[4];
    const float* W2   = (const float*)d_in[5];
    const float* b2   = (const float*)d_in[6];

    float* out_cur2 = (float*)d_out;                            // [T,B,1] flat
    float* out_spk  = (float*)d_out + (size_t)T_STEPS * BATCH;  // [T,B,200] flat

    rsnn_kernel<<<BATCH, 64, 0, stream>>>(X, W1, b1, Wrec, brec, W2, b2,
                                          out_cur2, out_spk);
}